// Round 7
// baseline (763.305 us; speedup 1.0000x reference)
//
#include <hip/hip_runtime.h>
#include <hip/hip_bf16.h>
#include <stdint.h>

// ---- types ----
typedef __bf16 bf16x8 __attribute__((ext_vector_type(8)));
typedef float  floatx4 __attribute__((ext_vector_type(4)));

#define NEG_BIG (-1e30f)   // finite sentinel: exp(NEG_BIG - m) == 0

// async global->LDS, 16B per lane; LDS dest = wave-uniform base + lane*16
#define GLD16(g, l) __builtin_amdgcn_global_load_lds(                         \
    (__attribute__((address_space(1))) void*)(g),                             \
    (__attribute__((address_space(3))) void*)(l), 16, 0, 0)

// convert 16 fp32 -> 16 bf16, store 32B to LDS
__device__ __forceinline__ void cvt16(const float* __restrict__ s,
                                      __hip_bfloat16* __restrict__ d) {
    float4 f[4];
#pragma unroll
    for (int i = 0; i < 4; i++) f[i] = ((const float4*)s)[i];
    union { __hip_bfloat16 h[16]; uint4 u[2]; } o;
#pragma unroll
    for (int i = 0; i < 4; i++) {
        o.h[4 * i + 0] = __float2bfloat16(f[i].x);
        o.h[4 * i + 1] = __float2bfloat16(f[i].y);
        o.h[4 * i + 2] = __float2bfloat16(f[i].z);
        o.h[4 * i + 3] = __float2bfloat16(f[i].w);
    }
    ((uint4*)d)[0] = o.u[0];
    ((uint4*)d)[1] = o.u[1];
}

// ============================================================================
// Fused fp32->bf16 convert of up to 3 arrays (grid-stride, 8 elems/thread).
// ============================================================================
__global__ __launch_bounds__(256)
void cvt3_f32_bf16(const float* __restrict__ a, size_t na8,
                   const float* __restrict__ b, size_t nb8,
                   const float* __restrict__ c, size_t nc8,
                   __hip_bfloat16* __restrict__ da,
                   __hip_bfloat16* __restrict__ db,
                   __hip_bfloat16* __restrict__ dc)
{
    const size_t total  = na8 + nb8 + nc8;
    const size_t stride = (size_t)gridDim.x * blockDim.x;
    for (size_t idx = (size_t)blockIdx.x * blockDim.x + threadIdx.x;
         idx < total; idx += stride) {
        const float* s; __hip_bfloat16* d; size_t o;
        if (idx < na8)            { s = a; d = da; o = idx; }
        else if (idx < na8 + nb8) { s = b; d = db; o = idx - na8; }
        else                      { s = c; d = dc; o = idx - na8 - nb8; }
        const float4 f0 = ((const float4*)s)[o * 2 + 0];
        const float4 f1 = ((const float4*)s)[o * 2 + 1];
        union { __hip_bfloat16 h[8]; uint4 u; } z;
        z.h[0] = __float2bfloat16(f0.x); z.h[1] = __float2bfloat16(f0.y);
        z.h[2] = __float2bfloat16(f0.z); z.h[3] = __float2bfloat16(f0.w);
        z.h[4] = __float2bfloat16(f1.x); z.h[5] = __float2bfloat16(f1.y);
        z.h[6] = __float2bfloat16(f1.z); z.h[7] = __float2bfloat16(f1.w);
        ((uint4*)d)[o] = z.u;
    }
}

// ============================================================================
// 128x192-tile NT GEMM, BK=32, 4 blocks/CU (QKV projection).
// 256 threads = 4 waves (2M x 2N), wave tile 64x96, acc[4][6] -> 24 MFMA per
// wave per K-tile (single ks, K=32 = one 16x16x32 MFMA per fragment pair).
// LDS = 2buf x (A 8KB + B 12KB) = 40KB -> exactly 4 blocks/CU (160KB).
// 4 barrier-independent blocks/CU decorrelate stalls (extends R5's 2-block
// m114 mechanism; R6 counters: 28% of cycles neither MFMA nor VALU issued).
//
// Per K-tile t: {10x ds_read(cur) | bar | lgkm0 | stage(t+2 -> cur, 5 loads)
//   | prio1 | 24 MFMA | prio0 | vmcnt(5) | bar}.
// Depth-2 prefetch: t+1 staged during t-1; during t we stage t+2 into cur
// (cur's ds_reads were all issued pre-bar, and GLD16 write-back arrives
// >=200cy later -- same skew safety as the R4/R5 schedule). Outstanding at
// vmcnt = t+1(5) + t+2(5) = 10 -> vmcnt(5) waits exactly for t+1. Never
// drains in-loop.
// XOR swizzle (both sides): 32-elem rows = 4 16B granules; LDS granule p of
// row r holds source granule p ^ (r&3); ds_read uses quad ^ (r&3). 16-lane
// column reads -> 2 lanes per 4-bank group = free (m136).
// XCD 2D chunk map: c=flat&7 owns by in [(c&1)*16,+16), bx in [(c>>1)*8,+8).
// ============================================================================
__global__ __launch_bounds__(256, 4)
void gemm4b_nt_bias(const __hip_bfloat16* __restrict__ A,
                    const __hip_bfloat16* __restrict__ B,
                    const float* __restrict__ bias,
                    __hip_bfloat16* __restrict__ C,
                    int M, int N, int K, int lda, int ldb)
{
    __shared__ __align__(16) __hip_bfloat16 Asm[2][128 * 32];
    __shared__ __align__(16) __hip_bfloat16 Bsm[2][192 * 32];

    // 2D XCD chunk mapping (grid 1024 = 32 x 32)
    const int flat = blockIdx.x;
    const int c    = flat & 7;          // XCD (round-robin dispatch)
    const int i_   = flat >> 3;         // 0..127 within chunk
    const int by = (c & 1) * 16 + (i_ & 15);
    const int bx = (c >> 1) * 8 + (i_ >> 4);
    const int m0 = by * 128, n0 = bx * 192;

    const int t    = threadIdx.x;
    const int wave = t >> 6, lane = t & 63;
    const int quad = lane >> 4, l16 = lane & 15;
    const int wr   = wave >> 1, wc = wave & 1;   // wave tile 64x96
    const int NT   = K >> 5;

    // ---- staging geometry: 4 threads/row (4 granules of 16B), 64 rows/call
    const int rloc = lane >> 2;          // row within wave's 16-row slice
    const int g_   = (lane & 3) ^ (rloc & 3);   // pre-swizzled source granule
    auto stageA = [&](int tk, int j, int buf) {
        const int row = j * 64 + wave * 16 + rloc;
        GLD16(A + (size_t)(m0 + row) * lda + tk * 32 + g_ * 8,
              &Asm[buf][0] + (j * 64 + wave * 16) * 32);
    };
    auto stageB = [&](int tk, int j, int buf) {
        const int row = j * 64 + wave * 16 + rloc;
        GLD16(B + (size_t)(n0 + row) * ldb + tk * 32 + g_ * 8,
              &Bsm[buf][0] + (j * 64 + wave * 16) * 32);
    };

    // ds_read swizzled granule (row&3 == l16&3 for all fragment rows)
    const int g0 = (quad ^ (l16 & 3)) << 3;   // bf16 element offset

    floatx4 acc[4][6];
    const floatx4 zero = {0.f, 0.f, 0.f, 0.f};
#pragma unroll
    for (int mi = 0; mi < 4; mi++)
#pragma unroll
        for (int ni = 0; ni < 6; ni++) acc[mi][ni] = zero;

    // ---- prologue: t0 (5 loads) + t1 (5); vmcnt(5) -> t0 resident ----
#pragma unroll
    for (int j = 0; j < 2; j++) stageA(0, j, 0);
#pragma unroll
    for (int j = 0; j < 3; j++) stageB(0, j, 0);
    if (NT > 1) {
#pragma unroll
        for (int j = 0; j < 2; j++) stageA(1, j, 1);
#pragma unroll
        for (int j = 0; j < 3; j++) stageB(1, j, 1);
        asm volatile("s_waitcnt vmcnt(5)" ::: "memory");
    } else {
        asm volatile("s_waitcnt vmcnt(0)" ::: "memory");
    }
    __syncthreads();

    int cb = 0;
    for (int tk = 0; tk < NT; ++tk, cb ^= 1) {
        const __hip_bfloat16* Ab = &Asm[cb][0];
        const __hip_bfloat16* Bb = &Bsm[cb][0];

        bf16x8 af[4], bfr[6];
#pragma unroll
        for (int i = 0; i < 4; i++)
            af[i] = *(const bf16x8*)(Ab + (wr * 64 + i * 16 + l16) * 32 + g0);
#pragma unroll
        for (int ni = 0; ni < 6; ni++)
            bfr[ni] = *(const bf16x8*)(Bb + (wc * 96 + ni * 16 + l16) * 32 + g0);

        __builtin_amdgcn_s_barrier();
        asm volatile("s_waitcnt lgkmcnt(0)" ::: "memory");
        if (tk + 2 < NT) {   // stage t+2 into cur (all cur reads issued pre-bar)
#pragma unroll
            for (int j = 0; j < 2; j++) stageA(tk + 2, j, cb);
#pragma unroll
            for (int j = 0; j < 3; j++) stageB(tk + 2, j, cb);
        }
        __builtin_amdgcn_s_setprio(1);
#pragma unroll
        for (int i = 0; i < 4; i++)
#pragma unroll
            for (int ni = 0; ni < 6; ni++)
                acc[i][ni] = __builtin_amdgcn_mfma_f32_16x16x32_bf16(
                    af[i], bfr[ni], acc[i][ni], 0, 0, 0);
        __builtin_amdgcn_s_setprio(0);
        if (tk + 2 < NT)
            asm volatile("s_waitcnt vmcnt(5)" ::: "memory");
        else if (tk + 1 < NT)
            asm volatile("s_waitcnt vmcnt(0)" ::: "memory");
        __builtin_amdgcn_s_barrier();
    }

#pragma unroll
    for (int mi = 0; mi < 4; mi++) {
        const int row = m0 + wr * 64 + mi * 16 + quad * 4;
#pragma unroll
        for (int ni = 0; ni < 6; ni++) {
            const int col = n0 + wc * 96 + ni * 16 + l16;
            const float bv = bias[col];
#pragma unroll
            for (int r = 0; r < 4; r++)
                C[(size_t)(row + r) * N + col] =
                    __float2bfloat16(acc[mi][ni][r] + bv);
        }
    }
}

// ============================================================================
// 128x128-tile NT GEMM, BK=32, 4 blocks/CU capacity, f32 out (out-proj).
// Same schedule as gemm4b; A,B = 2 staging calls each (4 loads/tile),
// vmcnt(4) = t+2's 4 in flight, t+1 resident. LDS = 2buf x (8+8)KB = 32KB.
// Grid 512 at 4-block capacity -> exactly 2 resident blocks/CU, balanced.
// ============================================================================
__global__ __launch_bounds__(256, 4)
void gemm4b128_nt_bias(const __hip_bfloat16* __restrict__ A,
                       const __hip_bfloat16* __restrict__ B,
                       const float* __restrict__ bias,
                       float* __restrict__ C,
                       int M, int N, int K, int lda, int ldb)
{
    __shared__ __align__(16) __hip_bfloat16 Asm[2][128 * 32];
    __shared__ __align__(16) __hip_bfloat16 Bsm[2][128 * 32];

    const int flat = blockIdx.x;
    const int c    = flat & 7;
    const int i_   = flat >> 3;          // 0..63
    const int by = (c & 3) * 8 + (i_ & 7);
    const int bx = (c >> 2) * 8 + (i_ >> 3);
    const int m0 = by * 128, n0 = bx * 128;

    const int t    = threadIdx.x;
    const int wave = t >> 6, lane = t & 63;
    const int quad = lane >> 4, l16 = lane & 15;
    const int wr   = wave >> 1, wc = wave & 1;   // wave tile 64x64
    const int NT   = K >> 5;

    const int rloc = lane >> 2;
    const int g_   = (lane & 3) ^ (rloc & 3);
    auto stageA = [&](int tk, int j, int buf) {
        const int row = j * 64 + wave * 16 + rloc;
        GLD16(A + (size_t)(m0 + row) * lda + tk * 32 + g_ * 8,
              &Asm[buf][0] + (j * 64 + wave * 16) * 32);
    };
    auto stageB = [&](int tk, int j, int buf) {
        const int row = j * 64 + wave * 16 + rloc;
        GLD16(B + (size_t)(n0 + row) * ldb + tk * 32 + g_ * 8,
              &Bsm[buf][0] + (j * 64 + wave * 16) * 32);
    };

    const int g0 = (quad ^ (l16 & 3)) << 3;

    floatx4 acc[4][4];
    const floatx4 zero = {0.f, 0.f, 0.f, 0.f};
#pragma unroll
    for (int mi = 0; mi < 4; mi++)
#pragma unroll
        for (int ni = 0; ni < 4; ni++) acc[mi][ni] = zero;

#pragma unroll
    for (int j = 0; j < 2; j++) { stageA(0, j, 0); stageB(0, j, 0); }
    if (NT > 1) {
#pragma unroll
        for (int j = 0; j < 2; j++) { stageA(1, j, 1); stageB(1, j, 1); }
        asm volatile("s_waitcnt vmcnt(4)" ::: "memory");
    } else {
        asm volatile("s_waitcnt vmcnt(0)" ::: "memory");
    }
    __syncthreads();

    int cb = 0;
    for (int tk = 0; tk < NT; ++tk, cb ^= 1) {
        const __hip_bfloat16* Ab = &Asm[cb][0];
        const __hip_bfloat16* Bb = &Bsm[cb][0];

        bf16x8 af[4], bfr[4];
#pragma unroll
        for (int i = 0; i < 4; i++)
            af[i] = *(const bf16x8*)(Ab + (wr * 64 + i * 16 + l16) * 32 + g0);
#pragma unroll
        for (int ni = 0; ni < 4; ni++)
            bfr[ni] = *(const bf16x8*)(Bb + (wc * 64 + ni * 16 + l16) * 32 + g0);

        __builtin_amdgcn_s_barrier();
        asm volatile("s_waitcnt lgkmcnt(0)" ::: "memory");
        if (tk + 2 < NT) {
#pragma unroll
            for (int j = 0; j < 2; j++) { stageA(tk + 2, j, cb); stageB(tk + 2, j, cb); }
        }
        __builtin_amdgcn_s_setprio(1);
#pragma unroll
        for (int i = 0; i < 4; i++)
#pragma unroll
            for (int ni = 0; ni < 4; ni++)
                acc[i][ni] = __builtin_amdgcn_mfma_f32_16x16x32_bf16(
                    af[i], bfr[ni], acc[i][ni], 0, 0, 0);
        __builtin_amdgcn_s_setprio(0);
        if (tk + 2 < NT)
            asm volatile("s_waitcnt vmcnt(4)" ::: "memory");
        else if (tk + 1 < NT)
            asm volatile("s_waitcnt vmcnt(0)" ::: "memory");
        __builtin_amdgcn_s_barrier();
    }

#pragma unroll
    for (int mi = 0; mi < 4; mi++) {
        const int row = m0 + wr * 64 + mi * 16 + quad * 4;
#pragma unroll
        for (int ni = 0; ni < 4; ni++) {
            const int col = n0 + wc * 64 + ni * 16 + l16;
            const float bv = bias[col];
#pragma unroll
            for (int r = 0; r < 4; r++)
                C[(size_t)(row + r) * N + col] = acc[mi][ni][r] + bv;
        }
    }
}

// ============================================================================
// 128x128 NT GEMM (m97 structure) — fp32 fallback path only.
// ============================================================================
template <bool A_F32, bool B_F32, bool OUT_F32>
__global__ __launch_bounds__(256, 2)
void gemm_nt_bias(const void* __restrict__ Av, const void* __restrict__ Bv,
                  const float* __restrict__ bias, void* __restrict__ Cv,
                  int M, int N, int K, int lda, int ldb)
{
    __shared__ __align__(16) __hip_bfloat16 Asm[128 * 32];
    __shared__ __align__(16) __hip_bfloat16 Bsm[128 * 32];
    const int m0   = blockIdx.y * 128;
    const int n0   = blockIdx.x * 128;
    const int t    = threadIdx.x;
    const int wave = t >> 6, lane = t & 63;
    const int quad = lane >> 4, l16 = lane & 15;
    const int wr   = wave >> 1, wc = wave & 1;

    floatx4 zero = {0.f, 0.f, 0.f, 0.f};
    floatx4 acc[4][4];
    for (int i = 0; i < 4; i++)
        for (int j = 0; j < 4; j++) acc[i][j] = zero;

    for (int k0 = 0; k0 < K; k0 += 32) {
        if (A_F32) {
            const float* A = (const float*)Av;
            const int row = t >> 1, half = t & 1;
            cvt16(A + (size_t)(m0 + row) * lda + k0 + half * 16,
                  Asm + row * 32 + half * 16);
        } else {
            const __hip_bfloat16* A = (const __hip_bfloat16*)Av;
            for (int j = 0; j < 2; ++j) {
                const int chunk = (wave * 2 + j) * 64 + lane;
                const int row   = chunk >> 2;
                const int kc    = chunk & 3;
                GLD16(A + (size_t)(m0 + row) * lda + k0 + kc * 8,
                      Asm + (wave * 2 + j) * 512);
            }
        }
        if (B_F32) {
            const float* B = (const float*)Bv;
            const int row = t >> 1, half = t & 1;
            cvt16(B + (size_t)(n0 + row) * ldb + k0 + half * 16,
                  Bsm + row * 32 + half * 16);
        } else {
            const __hip_bfloat16* B = (const __hip_bfloat16*)Bv;
            for (int j = 0; j < 2; ++j) {
                const int chunk = (wave * 2 + j) * 64 + lane;
                const int row   = chunk >> 2;
                const int kc    = chunk & 3;
                GLD16(B + (size_t)(n0 + row) * ldb + k0 + kc * 8,
                      Bsm + (wave * 2 + j) * 512);
            }
        }
        __syncthreads();

        bf16x8 af[4], bf[4];
        for (int i = 0; i < 4; i++) {
            af[i] = *(const bf16x8*)(Asm + (wr * 64 + i * 16 + l16) * 32 + quad * 8);
            bf[i] = *(const bf16x8*)(Bsm + (wc * 64 + i * 16 + l16) * 32 + quad * 8);
        }
        for (int mi = 0; mi < 4; mi++)
            for (int ni = 0; ni < 4; ni++)
                acc[mi][ni] = __builtin_amdgcn_mfma_f32_16x16x32_bf16(
                    af[mi], bf[ni], acc[mi][ni], 0, 0, 0);
        __syncthreads();
    }

    for (int mi = 0; mi < 4; mi++) {
        const int row = m0 + wr * 64 + mi * 16 + quad * 4;
        for (int ni = 0; ni < 4; ni++) {
            const int col = n0 + wc * 64 + ni * 16 + l16;
            const float bv = bias[col];
            for (int r = 0; r < 4; r++) {
                const float v = acc[mi][ni][r] + bv;
                if (OUT_F32)
                    ((float*)Cv)[(size_t)(row + r) * N + col] = v;
                else
                    ((__hip_bfloat16*)Cv)[(size_t)(row + r) * N + col] =
                        __float2bfloat16(v);
            }
        }
    }
}

// ============================================================================
// V permutation (unchanged): Vpt[b][h][sb32][hd][ss32], 8KB blobs.
// ============================================================================
__global__ __launch_bounds__(256)
void permute_v(const __hip_bfloat16* __restrict__ QKV,
               __hip_bfloat16* __restrict__ Vpt)
{
    __shared__ __align__(16) __hip_bfloat16 S[64 * 64];
    const int blk = blockIdx.x;
    const int sb = blk & 31, h = (blk >> 5) & 15, b = blk >> 9;
    const int t = threadIdx.x;

    for (int j = 0; j < 2; j++) {
        const int chunk = j * 256 + t;
        const int lrow  = chunk >> 3;
        const int lcol  = (chunk & 7) * 8;
        const int r8 = lrow >> 3, jj = lrow & 7;
        const int srow = r8 * 128 + h * 8 + jj;
        const int scol = sb * 64 + lcol;
        *(uint4*)(S + chunk * 8) =
            *(const uint4*)(QKV + ((size_t)(b * 1024) + srow) * 6144 + 4096 + scol);
    }
    __syncthreads();

    const size_t obase = (((size_t)(b * 16 + h)) * 32 + sb) * 4096;
    for (int i = 0; i < 16; i++) {
        const int lin = t + 256 * i;
        const int hd = lin >> 5, ss = lin & 31;
        Vpt[obase + lin] =
            S[((ss & 7) * 8 + (hd >> 4)) * 64 + (ss >> 3) * 16 + (hd & 15)];
    }
}

// ============================================================================
// Causal flash attention v3 (unchanged from R6).
// ============================================================================
__global__ __launch_bounds__(256, 2)
void flash_attn(const __hip_bfloat16* __restrict__ QKV,
                const __hip_bfloat16* __restrict__ Vpt,
                __hip_bfloat16* __restrict__ O)   // == QKV buffer
{
    __shared__ __align__(16) __hip_bfloat16 Kt[2][64 * 128];
    __shared__ __align__(16) __hip_bfloat16 Vt[2][2 * 128 * 32];
    __shared__ __align__(16) __hip_bfloat16 Pl[64 * 64];

    const int bid  = blockIdx.x;
    const int pair = bid >> 6;
    const int g    = bid & 63;
    const int b    = g >> 4, h = g & 15;
    const int t    = threadIdx.x;
    const int wave = t >> 6, lane = t & 63;
    const int quad = lane >> 4, l16 = lane & 15;
    const float scale = 0.08838834764831845f;

    const int    rowb  = b * 1024;
    const size_t vbase = (((size_t)(b * 16 + h)) * 32) * 4096;
    const floatx4 zero = {0.f, 0.f, 0.f, 0.f};

    auto stageK = [&](int tk, int bufi) {
        const int kv0 = tk * 64;
        __hip_bfloat16* dst = &Kt[bufi][0];
#pragma unroll
        for (int j = 0; j < 4; j++) {
            const int c0 = (wave * 4 + j) * 64 + lane;
            const int r  = c0 >> 4;
            const int gg = (c0 & 15) ^ (r & 7);
            GLD16(QKV + ((size_t)(rowb + kv0 + r)) * 6144 + 2048 + h * 128 + gg * 8,
                  dst + (wave * 4 + j) * 512);
        }
    };
    auto stageV = [&](int tk, int bufi) {
        const __hip_bfloat16* src = Vpt + vbase + (size_t)(tk * 2) * 4096;
        __hip_bfloat16* dst = &Vt[bufi][0];
#pragma unroll
        for (int j = 0; j < 4; j++) {
            const int c0   = (wave * 4 + j) * 64 + lane;
            const int half = c0 >> 9, w = c0 & 511;
            const int r    = w >> 2;
            const int gg   = (w & 3) ^ (r & 3);
            GLD16(src + half * 4096 + r * 32 + gg * 8,
                  dst + (wave * 4 + j) * 512);
        }
    };

    for (int ph = 0; ph < 2; ++ph) {
        const int qb = ph ? (15 - pair) * 64 : pair * 64;
        const int nt = ph ? 16 - pair       : pair + 1;

        bf16x8 qf[4];
        {
            const size_t rb = ((size_t)(rowb + qb + wave * 16 + l16)) * 6144 + h * 128;
#pragma unroll
            for (int kc = 0; kc < 4; kc++)
                qf[kc] = *(const bf16x8*)(QKV + rb + kc * 32 + quad * 8);
        }

        float m_i[4], l_i[4];    // l_i: per-thread partial (this lane's cols)
        floatx4 oacc[8];
#pragma unroll
        for (int r = 0; r < 4; r++) { m_i[r] = NEG_BIG; l_i[r] = 0.f; }
#pragma unroll
        for (int ni = 0; ni < 8; ni++) oacc[ni] = zero;

        stageK(0, 0); stageV(0, 0);

        for (int tk = 0; tk < nt; ++tk) {
            const int cur = tk & 1;
            if (tk + 1 < nt) {
                stageK(tk + 1, cur ^ 1); stageV(tk + 1, cur ^ 1);
                asm volatile("s_waitcnt vmcnt(8)" ::: "memory");
            } else {
                asm volatile("s_waitcnt vmcnt(0)" ::: "memory");
            }
            __builtin_amdgcn_s_barrier();
            asm volatile("" ::: "memory");

            const __hip_bfloat16* Kb = &Kt[cur][0];
            const __hip_bfloat16* Vb = &Vt[cur][0];
            const int kv0 = tk * 64;

            floatx4 sc[4];
#pragma unroll
            for (int cbk = 0; cbk < 4; cbk++) {
                floatx4 s = zero;
                const int r  = cbk * 16 + l16;
                const int sw = r & 7;
#pragma unroll
                for (int kc = 0; kc < 4; kc++) {
                    bf16x8 kf = *(const bf16x8*)(
                        Kb + r * 128 + (((kc * 4 + quad) ^ sw) << 3));
                    s = __builtin_amdgcn_mfma_f32_16x16x32_bf16(qf[kc], kf, s, 0, 0, 0);
                }
                sc[cbk] = s;
            }

            const int qrow = qb + wave * 16 + quad * 4;
            if (tk == nt - 1) {
#pragma unroll
                for (int rr = 0; rr < 4; rr++)
#pragma unroll
                    for (int cbk = 0; cbk < 4; cbk++) {
                        const int col = kv0 + cbk * 16 + l16;
                        const float v = sc[cbk][rr] * scale;
                        sc[cbk][rr] = (col > qrow + rr) ? NEG_BIG : v;
                    }
            } else {
#pragma unroll
                for (int rr = 0; rr < 4; rr++)
#pragma unroll
                    for (int cbk = 0; cbk < 4; cbk++) sc[cbk][rr] *= scale;
            }
            float mx[4];
#pragma unroll
            for (int rr = 0; rr < 4; rr++)
                mx[rr] = fmaxf(fmaxf(sc[0][rr], sc[1][rr]),
                               fmaxf(sc[2][rr], sc[3][rr]));
#pragma unroll
            for (int off = 1; off < 16; off <<= 1)
#pragma unroll
                for (int rr = 0; rr < 4; rr++)
                    mx[rr] = fmaxf(mx[rr], __shfl_xor(mx[rr], off));

            bool grow = false;
#pragma unroll
            for (int rr = 0; rr < 4; rr++)
                grow = grow || (mx[rr] > m_i[rr] + 8.0f);
            if (__any((int)grow)) {
#pragma unroll
                for (int rr = 0; rr < 4; rr++) {
                    const float mnew  = fmaxf(m_i[rr], mx[rr]);
                    const float alpha = __expf(m_i[rr] - mnew);
                    m_i[rr] = mnew;
                    float lsum = 0.f;
#pragma unroll
                    for (int cbk = 0; cbk < 4; cbk++) {
                        const float pv = __expf(sc[cbk][rr] - mnew);
                        sc[cbk][rr] = pv;
                        lsum += pv;
                    }
                    l_i[rr] = l_i[rr] * alpha + lsum;
#pragma unroll
                    for (int ni = 0; ni < 8; ni++) oacc[ni][rr] *= alpha;
                }
            } else {
#pragma unroll
                for (int rr = 0; rr < 4; rr++) {
                    float lsum = 0.f;
#pragma unroll
                    for (int cbk = 0; cbk < 4; cbk++) {
                        const float pv = __expf(sc[cbk][rr] - m_i[rr]);
                        sc[cbk][rr] = pv;
                        lsum += pv;
                    }
                    l_i[rr] += lsum;
                }
            }

#pragma unroll
            for (int cbk = 0; cbk < 4; cbk++)
#pragma unroll
                for (int rr = 0; rr < 4; rr++) {
                    const int row = wave * 16 + quad * 4 + rr;
                    const int col = cbk * 16 + l16;
                    Pl[row * 64 + ((((col >> 3) ^ (row & 7)) << 3) | (col & 7))] =
                        __float2bfloat16(sc[cbk][rr]);
                }
            asm volatile("s_waitcnt lgkmcnt(0)" ::: "memory");

            const int prow = wave * 16 + l16;
            bf16x8 pf[2];
#pragma unroll
            for (int kc = 0; kc < 2; kc++)
                pf[kc] = *(const bf16x8*)(
                    Pl + prow * 64 + (((kc * 4 + quad) ^ (prow & 7)) << 3));
#pragma unroll
            for (int ni = 0; ni < 8; ni++) {
                const int vr = ni * 16 + l16;
#pragma unroll
                for (int kc = 0; kc < 2; kc++) {
                    bf16x8 vf = *(const bf16x8*)(
                        Vb + kc * 4096 + vr * 32 + (((quad ^ (vr & 3))) << 3));
                    oacc[ni] = __builtin_amdgcn_mfma_f32_16x16x32_bf16(
                        pf[kc], vf, oacc[ni], 0, 0, 0);
                }
            }

            asm volatile("" ::: "memory");
            __builtin_amdgcn_s_barrier();
            asm volatile("" ::: "memory");
        }

#pragma unroll
        for (int off = 1; off < 16; off <<= 1)
#pragma unroll
            for (int rr = 0; rr < 4; rr++)
                l_i[rr] += __shfl_xor(l_i[rr], off);
        float inv[4];
#pragma unroll
        for (int rr = 0; rr < 4; rr++) inv[rr] = 1.0f / l_i[rr];
#pragma unroll
        for (int ni = 0; ni < 8; ni++)
#pragma unroll
            for (int rr = 0; rr < 4; rr++) {
                const int row = qb + wave * 16 + quad * 4 + rr;
                O[((size_t)rowb + row) * 6144 + 4096 + h * 128 + ni * 16 + l16] =
                    __float2bfloat16(oacc[ni][rr] * inv[rr]);
            }
    }
}

// ============================================================================
extern "C" void kernel_launch(void* const* d_in, const int* in_sizes, int n_in,
                              void* d_out, int out_size, void* d_ws, size_t ws_size,
                              hipStream_t stream) {
    const float* query = (const float*)d_in[0];
    const float* Wqkv = (const float*)d_in[3];
    const float* bqkv = (const float*)d_in[4];
    const float* Wout = (const float*)d_in[5];
    const float* bout = (const float*)d_in[6];
    float* out = (float*)d_out;

    const size_t MB = 1048576;
    char* ws = (char*)d_ws;
    __hip_bfloat16* QKV = (__hip_bfloat16*)ws;
    __hip_bfloat16* Vpt = (__hip_bfloat16*)(ws + 48 * MB);
    __hip_bfloat16* Att = QKV + 4096;            // column offset, lda = 6144

    dim3 blk(256);

    if (ws_size >= 113 * MB) {
        __hip_bfloat16* Qbf     = (__hip_bfloat16*)(ws + 64 * MB);
        __hip_bfloat16* Wqkv_bf = (__hip_bfloat16*)(ws + 80 * MB);
        __hip_bfloat16* Wout_bf = (__hip_bfloat16*)(ws + 104 * MB);

        cvt3_f32_bf16<<<dim3(2048), blk, 0, stream>>>(
            query, (size_t)4096 * 2048 / 8,
            Wqkv,  (size_t)6144 * 2048 / 8,
            Wout,  (size_t)2048 * 2048 / 8,
            Qbf, Wqkv_bf, Wout_bf);
        // QKV projection: 128x192 tiles, BK=32, grid 1024, 4 blocks/CU
        gemm4b_nt_bias<<<dim3(1024), dim3(256), 0, stream>>>(
            Qbf, Wqkv_bf, bqkv, QKV, 4096, 6144, 2048, 2048, 2048);
        permute_v<<<dim3(2048), blk, 0, stream>>>(QKV, Vpt);
        flash_attn<<<dim3(512), blk, 0, stream>>>(QKV, Vpt, QKV);
        // out projection: 128x128 tiles, BK=32, grid 512, 2 resident/CU
        gemm4b128_nt_bias<<<dim3(512), dim3(256), 0, stream>>>(
            Att, Wout_bf, bout, out, 4096, 2048, 2048, 6144, 2048);
    } else {
        gemm_nt_bias<true, true, false><<<dim3(48, 32), blk, 0, stream>>>(
            query, Wqkv, bqkv, QKV, 4096, 6144, 2048, 2048, 2048);
        permute_v<<<dim3(2048), blk, 0, stream>>>(QKV, Vpt);
        flash_attn<<<dim3(512), blk, 0, stream>>>(QKV, Vpt, QKV);
        gemm_nt_bias<false, true, true><<<dim3(16, 32), blk, 0, stream>>>(
            Att, Wout, bout, out, 4096, 2048, 2048, 6144, 2048);
    }
}